// Round 12
// baseline (57.717 us; speedup 1.0000x reference)
//
#include <hip/hip_runtime.h>

// SymbolicTraversal: out[b, n] = max(0, max_{e: type[e]==r_index[b], dst[e]==n} h[b, src[e]])
//
// R11: ATTRIBUTION ROUND. Exact R9 structure (best: 32.2us), but phase1 is launched
// 3x (idempotent: rewrites the same segment/overflow content; phase2 max-reduces an
// unordered record set, so order differences are immaterial). The bench delta gives
// phase1's standalone duration: p1 = (dur - 32.2)/2. This un-masks the per-phase
// split that rocprof top-5 hides behind the harness's 256MB ws fills.
//   phase1: 512 blocks x 1024 thr, stream edges, relation->batch bitmask filter,
//           LDS queues -> 64B segment flush, no global atomics.
//   phase2: 400 blocks x 1024 thr, wave-shaped (segment,word) apply, 16KB LDS slice,
//           plain coalesced store.
// Record: ((dst & 4095) << 17) | src  (needs N <= 2^17, guarded).

typedef int v4i __attribute__((ext_vector_type(4)));

#define NB1 512
#define TH1 1024
#define TH2 1024
#define QCAP 15
#define CSHIFT 12
#define MAXNBKT 448
#define OVCAP 16384

__global__ __launch_bounds__(TH1)
void phase1_kernel(const int* __restrict__ edge_index, // [2][E]
                   const int* __restrict__ etype,      // [E]
                   const int* __restrict__ r_index,    // [B]
                   unsigned int* __restrict__ ovcnt,   // [NB1] raw counts
                   uint2* __restrict__ ovrec,          // [NB1][OVCAP]
                   unsigned int* __restrict__ store,   // [nbkt][NB1][16]
                   int B, int N, int E, int nchunk, int nbkt) {
    __shared__ unsigned int smask[64];
    __shared__ unsigned int lcnt[MAXNBKT];
    __shared__ unsigned int lq[MAXNBKT * QCAP];
    __shared__ unsigned int sov;

    const int t = threadIdx.x;
    const int bid = blockIdx.x;
    if (t < 64) {
        unsigned int m = 0;
        for (int b = 0; b < B; ++b)
            if (r_index[b] == t) m |= (1u << b);
        smask[t] = m;
    }
    for (int i = t; i < nbkt; i += TH1) lcnt[i] = 0;
    if (t == 0) sov = 0;
    __syncthreads();

    const int* __restrict__ src = edge_index;
    const int* __restrict__ dst = edge_index + E;
    const unsigned int cmask = (1u << CSHIFT) - 1u;
    const int nq = E >> 2;

    for (int q = bid * TH1 + t; q < nq; q += NB1 * TH1) {
        v4i tv = __builtin_nontemporal_load(reinterpret_cast<const v4i*>(etype) + q);
        v4i sv = __builtin_nontemporal_load(reinterpret_cast<const v4i*>(src) + q);
        v4i dv = __builtin_nontemporal_load(reinterpret_cast<const v4i*>(dst) + q);
        #pragma unroll
        for (int i = 0; i < 4; ++i) {
            unsigned int ty = (unsigned int)tv[i];
            unsigned int m = (ty < 64u) ? smask[ty] : 0u;
            if (!m) continue;
            unsigned int d = (unsigned int)dv[i];
            unsigned int s = (unsigned int)sv[i];
            unsigned int rec = ((d & cmask) << 17) | s;
            int cb = (int)(d >> CSHIFT);
            do {
                int b = __builtin_ctz(m); m &= m - 1;
                int bkt = b * nchunk + cb;
                unsigned int pos = atomicAdd(&lcnt[bkt], 1u);
                if (pos < QCAP) {
                    lq[bkt * QCAP + pos] = rec;
                } else {
                    unsigned int p2 = atomicAdd(&sov, 1u);
                    if (p2 < OVCAP) {
                        uint2 rr; rr.x = (d << 5) | (unsigned int)b; rr.y = s;
                        ovrec[(size_t)bid * OVCAP + p2] = rr;
                    } // beyond OVCAP: dropped; raw count > OVCAP triggers panic re-stream
                }
            } while (m);
        }
    }
    if (bid == 0) {  // tail edges (E % 4)
        for (int e = (nq << 2) + t; e < E; e += TH1) {
            unsigned int ty = (unsigned int)etype[e];
            unsigned int m = (ty < 64u) ? smask[ty] : 0u;
            unsigned int d = (unsigned int)dst[e];
            unsigned int s = (unsigned int)src[e];
            unsigned int rec = ((d & cmask) << 17) | s;
            int cb = (int)(d >> CSHIFT);
            while (m) {
                int b = __builtin_ctz(m); m &= m - 1;
                int bkt = b * nchunk + cb;
                unsigned int pos = atomicAdd(&lcnt[bkt], 1u);
                if (pos < QCAP) {
                    lq[bkt * QCAP + pos] = rec;
                } else {
                    unsigned int p2 = atomicAdd(&sov, 1u);
                    if (p2 < OVCAP) {
                        uint2 rr; rr.x = (d << 5) | (unsigned int)b; rr.y = s;
                        ovrec[(size_t)bid * OVCAP + p2] = rr;
                    }
                }
            }
        }
    }
    __syncthreads();

    if (t == 0) ovcnt[bid] = sov;  // raw (not clamped): >OVCAP means panic

    // Flush: each bucket -> one full 64B line. 16 lanes/bucket, 4 buckets/wave.
    const int wid = t >> 6, lane = t & 63;
    const int sub = lane >> 4, word = lane & 15;
    for (int k0 = wid * 4; k0 < nbkt; k0 += (TH1 / 64) * 4) {
        int k = k0 + sub;
        if (k < nbkt) {
            unsigned int n = lcnt[k]; if (n > QCAP) n = QCAP;
            unsigned int val = (word == 0) ? n : lq[k * QCAP + (word - 1)];
            store[((size_t)k * NB1 + bid) * 16 + word] = val;
        }
    }
}

__global__ __launch_bounds__(TH2)
void phase2_kernel(const float* __restrict__ h,
                   const unsigned int* __restrict__ store,
                   const unsigned int* __restrict__ ovcnt,
                   const uint2* __restrict__ ovrec,
                   const int* __restrict__ edge_index,
                   const int* __restrict__ etype,
                   const int* __restrict__ r_index,
                   int N, int E, int nchunk,
                   int* __restrict__ out) {
    __shared__ int slice[1 << CSHIFT];  // 16KB
    __shared__ int spanic;

    const int t = threadIdx.x;
    const int k = blockIdx.x;           // bucket
    const int b = k / nchunk;
    const int c = k % nchunk;
    const int csz = 1 << CSHIFT;
    const unsigned int cmask = (1u << CSHIFT) - 1u;

    for (int i = t; i < csz; i += TH2) slice[i] = 0;
    if (t == 0) spanic = 0;
    __syncthreads();

    const unsigned int* __restrict__ base = store + (size_t)k * NB1 * 16;
    const float* __restrict__ hb = h + (size_t)b * N;

    // Wave-shaped segment apply: lane reads word (t&15) of segment (t>>4).
    const int lane16 = t & 15;
    const int srcLane = (t & 63) & ~15;
    #pragma unroll 2
    for (int pass = 0; pass < NB1 / (TH2 / 16); ++pass) {
        int seg = pass * (TH2 / 16) + (t >> 4);
        unsigned int w = base[(size_t)seg * 16 + lane16];
        unsigned int n = (unsigned int)__shfl((int)w, srcLane, 64);
        if (n > QCAP) n = QCAP;
        if (lane16 >= 1 && (unsigned int)lane16 <= n) {
            int s  = (int)(w & 0x1FFFFu);
            int ld = (int)(w >> 17);
            atomicMax(&slice[ld], __float_as_int(hb[s]));
        }
    }

    // Overflow lists: thread r owns list r (counts ~0 in practice).
    for (int r = t; r < NB1; r += TH2) {
        unsigned int raw = ovcnt[r];
        if (raw > OVCAP) { atomicOr(&spanic, 1); raw = OVCAP; }
        const uint2* __restrict__ rp = ovrec + (size_t)r * OVCAP;
        for (unsigned int i = 0; i < raw; ++i) {
            uint2 rr = rp[i];
            int bb = (int)(rr.x & 31u);
            unsigned int d = rr.x >> 5;
            if (bb == b && (int)(d >> CSHIFT) == c)
                atomicMax(&slice[d & cmask], __float_as_int(hb[rr.y]));
        }
    }
    __syncthreads();

    if (spanic) {  // ultra-rare: re-stream all edges for this bucket (idempotent max)
        const int rb = r_index[b];
        const int* __restrict__ src = edge_index;
        const int* __restrict__ dst = edge_index + E;
        for (int e = t; e < E; e += TH2) {
            if (etype[e] == rb) {
                unsigned int d = (unsigned int)dst[e];
                if ((int)(d >> CSHIFT) == c)
                    atomicMax(&slice[d & cmask], __float_as_int(hb[src[e]]));
            }
        }
        __syncthreads();
    }

    // Plain coalesced store (out never read; covers clamp floor + empty segments).
    const int d0 = c << CSHIFT;
    int cnt = N - d0; if (cnt > csz) cnt = csz;
    int* __restrict__ ob = out + (size_t)b * N + d0;
    for (int i = t; i < cnt; i += TH2) ob[i] = slice[i];
}

// ===== Fallback for unsupported shapes / tiny ws =====

__global__ __launch_bounds__(256)
void zero_out_kernel(int* __restrict__ out, int n) {
    int i = (blockIdx.x * 256 + threadIdx.x) * 4;
    if (i + 3 < n) {
        v4i z = {0, 0, 0, 0};
        *reinterpret_cast<v4i*>(out + i) = z;
    } else {
        for (int j = i; j < n && j >= 0; ++j) out[j] = 0;
    }
}

__global__ __launch_bounds__(256)
void traverse_direct(const float* __restrict__ h,
                     const int* __restrict__ edge_index,
                     const int* __restrict__ etype,
                     const int* __restrict__ r_index,
                     int* __restrict__ out, int B, int N, int E) {
    __shared__ unsigned int smask[64];
    if (threadIdx.x < 64) {
        unsigned int m = 0;
        for (int b = 0; b < B; ++b)
            if (r_index[b] == (int)threadIdx.x) m |= (1u << b);
        smask[threadIdx.x] = m;
    }
    __syncthreads();
    const int* __restrict__ src = edge_index;
    const int* __restrict__ dst = edge_index + E;
    int e = blockIdx.x * blockDim.x + threadIdx.x;
    if (e < E) {
        unsigned int ty = (unsigned int)etype[e];
        unsigned int m = (ty < 64u) ? smask[ty] : 0u;
        while (m) {
            int b = __builtin_ctz(m); m &= m - 1;
            float v = h[(size_t)b * N + src[e]];
            atomicMax(out + (size_t)b * N + dst[e], __float_as_int(v));
        }
    }
}

extern "C" void kernel_launch(void* const* d_in, const int* in_sizes, int n_in,
                              void* d_out, int out_size, void* d_ws, size_t ws_size,
                              hipStream_t stream) {
    const float* h          = (const float*)d_in[0];
    const int*   edge_index = (const int*)d_in[1];
    const int*   etype      = (const int*)d_in[2];
    const int*   r_index    = (const int*)d_in[3];

    const int B = in_sizes[3];
    const int N = in_sizes[0] / B;
    const int E = in_sizes[2];
    const int nchunk = (N + (1 << CSHIFT) - 1) >> CSHIFT;
    const int nbkt = B * nchunk;
    int* out_i = (int*)d_out;

    // ws layout: ovcnt u32[NB1] (4KB pad) | store [nbkt][NB1][16] u32 | ovrec [NB1][OVCAP] uint2
    unsigned int* ovcnt = (unsigned int*)d_ws;
    unsigned int* store = ovcnt + 1024;
    const size_t store_words = (size_t)(nbkt > 0 ? nbkt : 1) * NB1 * 16;
    uint2* ovrec = (uint2*)(store + store_words);
    const size_t need_ws = 4096 + store_words * 4 + (size_t)NB1 * OVCAP * 8;

    const bool fast = (N <= (1 << 17)) && (B <= 32) && (nbkt >= 1) &&
                      (nbkt <= MAXNBKT) && (ws_size >= need_ws) && (E >= 4) &&
                      (out_size == B * N);
    if (fast) {
        // ATTRIBUTION: phase1 launched 3x (idempotent). p1 = (dur - dur_R9)/2.
        phase1_kernel<<<NB1, TH1, 0, stream>>>(
            edge_index, etype, r_index, ovcnt, ovrec, store,
            B, N, E, nchunk, nbkt);
        phase1_kernel<<<NB1, TH1, 0, stream>>>(
            edge_index, etype, r_index, ovcnt, ovrec, store,
            B, N, E, nchunk, nbkt);
        phase1_kernel<<<NB1, TH1, 0, stream>>>(
            edge_index, etype, r_index, ovcnt, ovrec, store,
            B, N, E, nchunk, nbkt);
        phase2_kernel<<<nbkt, TH2, 0, stream>>>(
            h, store, ovcnt, ovrec, edge_index, etype, r_index,
            N, E, nchunk, out_i);
    } else {
        const int nz = (out_size + 1023) / 1024;
        zero_out_kernel<<<nz, 256, 0, stream>>>(out_i, out_size);
        traverse_direct<<<(E + 255) / 256, 256, 0, stream>>>(
            h, edge_index, etype, r_index, out_i, B, N, E);
    }
}

// Round 13
// 39.807 us; speedup vs baseline: 1.4499x; 1.4499x over previous
//
#include <hip/hip_runtime.h>

// SymbolicTraversal: out[b, n] = max(0, max_{e: type[e]==r_index[b], dst[e]==n} h[b, src[e]])
//
// R12: finer buckets for phase2 balance/TLP. CSHIFT 12->11 (784 buckets, 8KB slices,
// 3.1 blocks/CU), QCAP 7 / SEGW 8 (32B segments, lambda~2.0). Same two-dispatch
// structure as R9: phase1 streams+filters edges into per-bucket LDS queues flushed as
// fixed segments (no global atomics); phase2 resolves each bucket in LDS and plain-
// stores out (never reads it).
// Record: ((dst & 2047) << 17) | src  (needs N <= 2^17, guarded).
// Overflow: per-block ws list; panic (> OVCAP, never expected) -> phase2 re-streams
// that bucket's edges (max idempotent). Fallback path for unsupported shapes.

typedef int v4i __attribute__((ext_vector_type(4)));

#define NB1 512
#define TH1 1024
#define TH2 1024
#define QCAP 7
#define SEGW 8
#define CSHIFT 11
#define MAXNBKT 800
#define OVCAP 16384

__global__ __launch_bounds__(TH1)
void phase1_kernel(const int* __restrict__ edge_index, // [2][E]
                   const int* __restrict__ etype,      // [E]
                   const int* __restrict__ r_index,    // [B]
                   unsigned int* __restrict__ ovcnt,   // [NB1] raw counts
                   uint2* __restrict__ ovrec,          // [NB1][OVCAP]
                   unsigned int* __restrict__ store,   // [nbkt][NB1][SEGW]
                   int B, int N, int E, int nchunk, int nbkt) {
    __shared__ unsigned int smask[64];
    __shared__ unsigned int lcnt[MAXNBKT];
    __shared__ unsigned int lq[MAXNBKT * QCAP];   // 800*7*4 = 22.4KB
    __shared__ unsigned int sov;

    const int t = threadIdx.x;
    const int bid = blockIdx.x;
    if (t < 64) {
        unsigned int m = 0;
        for (int b = 0; b < B; ++b)
            if (r_index[b] == t) m |= (1u << b);
        smask[t] = m;
    }
    for (int i = t; i < nbkt; i += TH1) lcnt[i] = 0;
    if (t == 0) sov = 0;
    __syncthreads();

    const int* __restrict__ src = edge_index;
    const int* __restrict__ dst = edge_index + E;
    const unsigned int cmask = (1u << CSHIFT) - 1u;
    const int nq = E >> 2;

    for (int q = bid * TH1 + t; q < nq; q += NB1 * TH1) {
        v4i tv = __builtin_nontemporal_load(reinterpret_cast<const v4i*>(etype) + q);
        v4i sv = __builtin_nontemporal_load(reinterpret_cast<const v4i*>(src) + q);
        v4i dv = __builtin_nontemporal_load(reinterpret_cast<const v4i*>(dst) + q);
        #pragma unroll
        for (int i = 0; i < 4; ++i) {
            unsigned int ty = (unsigned int)tv[i];
            unsigned int m = (ty < 64u) ? smask[ty] : 0u;
            if (!m) continue;
            unsigned int d = (unsigned int)dv[i];
            unsigned int s = (unsigned int)sv[i];
            unsigned int rec = ((d & cmask) << 17) | s;
            int cb = (int)(d >> CSHIFT);
            do {
                int b = __builtin_ctz(m); m &= m - 1;
                int bkt = b * nchunk + cb;
                unsigned int pos = atomicAdd(&lcnt[bkt], 1u);
                if (pos < QCAP) {
                    lq[bkt * QCAP + pos] = rec;
                } else {
                    unsigned int p2 = atomicAdd(&sov, 1u);
                    if (p2 < OVCAP) {
                        uint2 rr; rr.x = (d << 5) | (unsigned int)b; rr.y = s;
                        ovrec[(size_t)bid * OVCAP + p2] = rr;
                    } // beyond OVCAP: dropped; raw count > OVCAP triggers panic re-stream
                }
            } while (m);
        }
    }
    if (bid == 0) {  // tail edges (E % 4)
        for (int e = (nq << 2) + t; e < E; e += TH1) {
            unsigned int ty = (unsigned int)etype[e];
            unsigned int m = (ty < 64u) ? smask[ty] : 0u;
            unsigned int d = (unsigned int)dst[e];
            unsigned int s = (unsigned int)src[e];
            unsigned int rec = ((d & cmask) << 17) | s;
            int cb = (int)(d >> CSHIFT);
            while (m) {
                int b = __builtin_ctz(m); m &= m - 1;
                int bkt = b * nchunk + cb;
                unsigned int pos = atomicAdd(&lcnt[bkt], 1u);
                if (pos < QCAP) {
                    lq[bkt * QCAP + pos] = rec;
                } else {
                    unsigned int p2 = atomicAdd(&sov, 1u);
                    if (p2 < OVCAP) {
                        uint2 rr; rr.x = (d << 5) | (unsigned int)b; rr.y = s;
                        ovrec[(size_t)bid * OVCAP + p2] = rr;
                    }
                }
            }
        }
    }
    __syncthreads();

    if (t == 0) ovcnt[bid] = sov;  // raw (not clamped): >OVCAP means panic

    // Flush: each bucket -> one full 32B segment. 8 lanes/bucket, 8 buckets/wave.
    const int wid = t >> 6, lane = t & 63;
    const int sub = lane >> 3;       // 0..7
    const int word = lane & 7;       // 0..7
    for (int k0 = wid * 8; k0 < nbkt; k0 += (TH1 / 64) * 8) {
        int k = k0 + sub;
        if (k < nbkt) {
            unsigned int n = lcnt[k]; if (n > QCAP) n = QCAP;
            unsigned int val = (word == 0) ? n : lq[k * QCAP + (word - 1)];
            store[((size_t)k * NB1 + bid) * SEGW + word] = val;
        }
    }
}

__global__ __launch_bounds__(TH2)
void phase2_kernel(const float* __restrict__ h,
                   const unsigned int* __restrict__ store,
                   const unsigned int* __restrict__ ovcnt,
                   const uint2* __restrict__ ovrec,
                   const int* __restrict__ edge_index,
                   const int* __restrict__ etype,
                   const int* __restrict__ r_index,
                   int N, int E, int nchunk,
                   int* __restrict__ out) {
    __shared__ int slice[1 << CSHIFT];  // 8KB
    __shared__ int spanic;

    const int t = threadIdx.x;
    const int k = blockIdx.x;           // bucket
    const int b = k / nchunk;
    const int c = k % nchunk;
    const int csz = 1 << CSHIFT;
    const unsigned int cmask = (1u << CSHIFT) - 1u;

    for (int i = t; i < csz; i += TH2) slice[i] = 0;
    if (t == 0) spanic = 0;
    __syncthreads();

    const unsigned int* __restrict__ base = store + (size_t)k * NB1 * SEGW;
    const float* __restrict__ hb = h + (size_t)b * N;

    // Wave-shaped segment apply: lane reads word (t&7) of segment (t>>3).
    // Coalesced loads; count broadcast via shfl within the 8-lane group; active
    // lanes gather + LDS-atomic in parallel.
    const int lane8 = t & 7;
    const int srcLane = (t & 63) & ~7;
    #pragma unroll 2
    for (int pass = 0; pass < NB1 / (TH2 / SEGW); ++pass) {
        int seg = pass * (TH2 / SEGW) + (t >> 3);
        unsigned int w = base[(size_t)seg * SEGW + lane8];
        unsigned int n = (unsigned int)__shfl((int)w, srcLane, 64);
        if (n > QCAP) n = QCAP;
        if (lane8 >= 1 && (unsigned int)lane8 <= n) {
            int s  = (int)(w & 0x1FFFFu);
            int ld = (int)(w >> 17);
            atomicMax(&slice[ld], __float_as_int(hb[s]));
        }
    }

    // Overflow lists: thread r owns list r (counts ~0 in practice).
    for (int r = t; r < NB1; r += TH2) {
        unsigned int raw = ovcnt[r];
        if (raw > OVCAP) { atomicOr(&spanic, 1); raw = OVCAP; }
        const uint2* __restrict__ rp = ovrec + (size_t)r * OVCAP;
        for (unsigned int i = 0; i < raw; ++i) {
            uint2 rr = rp[i];
            int bb = (int)(rr.x & 31u);
            unsigned int d = rr.x >> 5;
            if (bb == b && (int)(d >> CSHIFT) == c)
                atomicMax(&slice[d & cmask], __float_as_int(hb[rr.y]));
        }
    }
    __syncthreads();

    if (spanic) {  // ultra-rare: re-stream all edges for this bucket (idempotent max)
        const int rb = r_index[b];
        const int* __restrict__ src = edge_index;
        const int* __restrict__ dst = edge_index + E;
        for (int e = t; e < E; e += TH2) {
            if (etype[e] == rb) {
                unsigned int d = (unsigned int)dst[e];
                if ((int)(d >> CSHIFT) == c)
                    atomicMax(&slice[d & cmask], __float_as_int(hb[src[e]]));
            }
        }
        __syncthreads();
    }

    // Plain coalesced store (out never read; covers clamp floor + empty segments).
    const int d0 = c << CSHIFT;
    int cnt = N - d0; if (cnt > csz) cnt = csz;
    int* __restrict__ ob = out + (size_t)b * N + d0;
    for (int i = t; i < cnt; i += TH2) ob[i] = slice[i];
}

// ===== Fallback for unsupported shapes / tiny ws =====

__global__ __launch_bounds__(256)
void zero_out_kernel(int* __restrict__ out, int n) {
    int i = (blockIdx.x * 256 + threadIdx.x) * 4;
    if (i + 3 < n) {
        v4i z = {0, 0, 0, 0};
        *reinterpret_cast<v4i*>(out + i) = z;
    } else {
        for (int j = i; j < n && j >= 0; ++j) out[j] = 0;
    }
}

__global__ __launch_bounds__(256)
void traverse_direct(const float* __restrict__ h,
                     const int* __restrict__ edge_index,
                     const int* __restrict__ etype,
                     const int* __restrict__ r_index,
                     int* __restrict__ out, int B, int N, int E) {
    __shared__ unsigned int smask[64];
    if (threadIdx.x < 64) {
        unsigned int m = 0;
        for (int b = 0; b < B; ++b)
            if (r_index[b] == (int)threadIdx.x) m |= (1u << b);
        smask[threadIdx.x] = m;
    }
    __syncthreads();
    const int* __restrict__ src = edge_index;
    const int* __restrict__ dst = edge_index + E;
    int e = blockIdx.x * blockDim.x + threadIdx.x;
    if (e < E) {
        unsigned int ty = (unsigned int)etype[e];
        unsigned int m = (ty < 64u) ? smask[ty] : 0u;
        while (m) {
            int b = __builtin_ctz(m); m &= m - 1;
            float v = h[(size_t)b * N + src[e]];
            atomicMax(out + (size_t)b * N + dst[e], __float_as_int(v));
        }
    }
}

extern "C" void kernel_launch(void* const* d_in, const int* in_sizes, int n_in,
                              void* d_out, int out_size, void* d_ws, size_t ws_size,
                              hipStream_t stream) {
    const float* h          = (const float*)d_in[0];
    const int*   edge_index = (const int*)d_in[1];
    const int*   etype      = (const int*)d_in[2];
    const int*   r_index    = (const int*)d_in[3];

    const int B = in_sizes[3];
    const int N = in_sizes[0] / B;
    const int E = in_sizes[2];
    const int nchunk = (N + (1 << CSHIFT) - 1) >> CSHIFT;
    const int nbkt = B * nchunk;
    int* out_i = (int*)d_out;

    // ws layout: ovcnt u32[NB1] (4KB pad) | store [nbkt][NB1][SEGW] u32 | ovrec [NB1][OVCAP] uint2
    unsigned int* ovcnt = (unsigned int*)d_ws;
    unsigned int* store = ovcnt + 1024;
    const size_t store_words = (size_t)(nbkt > 0 ? nbkt : 1) * NB1 * SEGW;
    uint2* ovrec = (uint2*)(store + store_words);
    const size_t need_ws = 4096 + store_words * 4 + (size_t)NB1 * OVCAP * 8;

    const bool fast = (N <= (1 << 17)) && (B <= 32) && (nbkt >= 1) &&
                      (nbkt <= MAXNBKT) && (ws_size >= need_ws) && (E >= 4) &&
                      (out_size == B * N);
    if (fast) {
        phase1_kernel<<<NB1, TH1, 0, stream>>>(
            edge_index, etype, r_index, ovcnt, ovrec, store,
            B, N, E, nchunk, nbkt);
        phase2_kernel<<<nbkt, TH2, 0, stream>>>(
            h, store, ovcnt, ovrec, edge_index, etype, r_index,
            N, E, nchunk, out_i);
    } else {
        const int nz = (out_size + 1023) / 1024;
        zero_out_kernel<<<nz, 256, 0, stream>>>(out_i, out_size);
        traverse_direct<<<(E + 255) / 256, 256, 0, stream>>>(
            h, edge_index, etype, r_index, out_i, B, N, E);
    }
}

// Round 14
// 28.670 us; speedup vs baseline: 2.0131x; 1.3884x over previous
//
#include <hip/hip_runtime.h>

// SymbolicTraversal: out[b, n] = max(0, max_{e: type[e]==r_index[b], dst[e]==n} h[b, src[e]])
//
// R13: R9 geometry (best, 32.2us) + XCD-locality swizzle in phase2.
//   Bucket decode changed from (b=k/nchunk, c=k%nchunk) to (b=k%B, c=k/B): with
//   B=16 and 8 XCDs, all blocks gathering from h-row b land on XCD b%8 (round-robin
//   dispatch heuristic; perf-only assumption). Each XCD's L2 then holds only 2 rows
//   (800KB) instead of demand-fetching all 16 (6.4MB x 8 XCDs redundant fill), and
//   the 790K phase2 h-gathers become local-L2 hits.
//   phase1: 512 x 1024, stream edges, relation->batch bitmask filter, LDS queues ->
//           64B segment flush {count, <=15 records}, no global atomics.
//   phase2: 400 x 1024, wave-shaped (segment,word) apply, 16KB LDS slice max,
//           plain coalesced store (out never read).
// Record: ((dst & 4095) << 17) | src  (needs N <= 2^17, guarded).
// Overflow: per-block ws list; panic (> OVCAP) -> re-stream bucket edges (idempotent).

typedef int v4i __attribute__((ext_vector_type(4)));

#define NB1 512
#define TH1 1024
#define TH2 1024
#define QCAP 15
#define CSHIFT 12
#define MAXNBKT 448
#define OVCAP 16384

__global__ __launch_bounds__(TH1)
void phase1_kernel(const int* __restrict__ edge_index, // [2][E]
                   const int* __restrict__ etype,      // [E]
                   const int* __restrict__ r_index,    // [B]
                   unsigned int* __restrict__ ovcnt,   // [NB1] raw counts
                   uint2* __restrict__ ovrec,          // [NB1][OVCAP]
                   unsigned int* __restrict__ store,   // [nbkt][NB1][16]
                   int B, int N, int E, int nchunk, int nbkt) {
    __shared__ unsigned int smask[64];
    __shared__ unsigned int lcnt[MAXNBKT];
    __shared__ unsigned int lq[MAXNBKT * QCAP];
    __shared__ unsigned int sov;

    const int t = threadIdx.x;
    const int bid = blockIdx.x;
    if (t < 64) {
        unsigned int m = 0;
        for (int b = 0; b < B; ++b)
            if (r_index[b] == t) m |= (1u << b);
        smask[t] = m;
    }
    for (int i = t; i < nbkt; i += TH1) lcnt[i] = 0;
    if (t == 0) sov = 0;
    __syncthreads();

    const int* __restrict__ src = edge_index;
    const int* __restrict__ dst = edge_index + E;
    const unsigned int cmask = (1u << CSHIFT) - 1u;
    const int nq = E >> 2;

    for (int q = bid * TH1 + t; q < nq; q += NB1 * TH1) {
        v4i tv = __builtin_nontemporal_load(reinterpret_cast<const v4i*>(etype) + q);
        v4i sv = __builtin_nontemporal_load(reinterpret_cast<const v4i*>(src) + q);
        v4i dv = __builtin_nontemporal_load(reinterpret_cast<const v4i*>(dst) + q);
        #pragma unroll
        for (int i = 0; i < 4; ++i) {
            unsigned int ty = (unsigned int)tv[i];
            unsigned int m = (ty < 64u) ? smask[ty] : 0u;
            if (!m) continue;
            unsigned int d = (unsigned int)dv[i];
            unsigned int s = (unsigned int)sv[i];
            unsigned int rec = ((d & cmask) << 17) | s;
            int cb = (int)(d >> CSHIFT);
            do {
                int b = __builtin_ctz(m); m &= m - 1;
                int bkt = b * nchunk + cb;
                unsigned int pos = atomicAdd(&lcnt[bkt], 1u);
                if (pos < QCAP) {
                    lq[bkt * QCAP + pos] = rec;
                } else {
                    unsigned int p2 = atomicAdd(&sov, 1u);
                    if (p2 < OVCAP) {
                        uint2 rr; rr.x = (d << 5) | (unsigned int)b; rr.y = s;
                        ovrec[(size_t)bid * OVCAP + p2] = rr;
                    } // beyond OVCAP: dropped; raw count > OVCAP triggers panic re-stream
                }
            } while (m);
        }
    }
    if (bid == 0) {  // tail edges (E % 4)
        for (int e = (nq << 2) + t; e < E; e += TH1) {
            unsigned int ty = (unsigned int)etype[e];
            unsigned int m = (ty < 64u) ? smask[ty] : 0u;
            unsigned int d = (unsigned int)dst[e];
            unsigned int s = (unsigned int)src[e];
            unsigned int rec = ((d & cmask) << 17) | s;
            int cb = (int)(d >> CSHIFT);
            while (m) {
                int b = __builtin_ctz(m); m &= m - 1;
                int bkt = b * nchunk + cb;
                unsigned int pos = atomicAdd(&lcnt[bkt], 1u);
                if (pos < QCAP) {
                    lq[bkt * QCAP + pos] = rec;
                } else {
                    unsigned int p2 = atomicAdd(&sov, 1u);
                    if (p2 < OVCAP) {
                        uint2 rr; rr.x = (d << 5) | (unsigned int)b; rr.y = s;
                        ovrec[(size_t)bid * OVCAP + p2] = rr;
                    }
                }
            }
        }
    }
    __syncthreads();

    if (t == 0) ovcnt[bid] = sov;  // raw (not clamped): >OVCAP means panic

    // Flush: each bucket -> one full 64B line. 16 lanes/bucket, 4 buckets/wave.
    const int wid = t >> 6, lane = t & 63;
    const int sub = lane >> 4, word = lane & 15;
    for (int k0 = wid * 4; k0 < nbkt; k0 += (TH1 / 64) * 4) {
        int k = k0 + sub;
        if (k < nbkt) {
            unsigned int n = lcnt[k]; if (n > QCAP) n = QCAP;
            unsigned int val = (word == 0) ? n : lq[k * QCAP + (word - 1)];
            store[((size_t)k * NB1 + bid) * 16 + word] = val;
        }
    }
}

__global__ __launch_bounds__(TH2)
void phase2_kernel(const float* __restrict__ h,
                   const unsigned int* __restrict__ store,
                   const unsigned int* __restrict__ ovcnt,
                   const uint2* __restrict__ ovrec,
                   const int* __restrict__ edge_index,
                   const int* __restrict__ etype,
                   const int* __restrict__ r_index,
                   int B, int N, int E, int nchunk,
                   int* __restrict__ out) {
    __shared__ int slice[1 << CSHIFT];  // 16KB
    __shared__ int spanic;

    const int t = threadIdx.x;
    // XCD-locality decode: blocks with the same batch b land on the same XCD
    // (bid % 8 heuristic; B % 8 == 0 guarded at launch).
    const int b = blockIdx.x % B;
    const int c = blockIdx.x / B;
    const int k = b * nchunk + c;       // bucket (store layout unchanged)
    const int csz = 1 << CSHIFT;
    const unsigned int cmask = (1u << CSHIFT) - 1u;

    for (int i = t; i < csz; i += TH2) slice[i] = 0;
    if (t == 0) spanic = 0;
    __syncthreads();

    const unsigned int* __restrict__ base = store + (size_t)k * NB1 * 16;
    const float* __restrict__ hb = h + (size_t)b * N;

    // Wave-shaped segment apply: lane reads word (t&15) of segment (t>>4).
    const int lane16 = t & 15;
    const int srcLane = (t & 63) & ~15;
    #pragma unroll 2
    for (int pass = 0; pass < NB1 / (TH2 / 16); ++pass) {
        int seg = pass * (TH2 / 16) + (t >> 4);
        unsigned int w = base[(size_t)seg * 16 + lane16];
        unsigned int n = (unsigned int)__shfl((int)w, srcLane, 64);
        if (n > QCAP) n = QCAP;
        if (lane16 >= 1 && (unsigned int)lane16 <= n) {
            int s  = (int)(w & 0x1FFFFu);
            int ld = (int)(w >> 17);
            atomicMax(&slice[ld], __float_as_int(hb[s]));
        }
    }

    // Overflow lists: thread r owns list r (counts ~0 in practice).
    for (int r = t; r < NB1; r += TH2) {
        unsigned int raw = ovcnt[r];
        if (raw > OVCAP) { atomicOr(&spanic, 1); raw = OVCAP; }
        const uint2* __restrict__ rp = ovrec + (size_t)r * OVCAP;
        for (unsigned int i = 0; i < raw; ++i) {
            uint2 rr = rp[i];
            int bb = (int)(rr.x & 31u);
            unsigned int d = rr.x >> 5;
            if (bb == b && (int)(d >> CSHIFT) == c)
                atomicMax(&slice[d & cmask], __float_as_int(hb[rr.y]));
        }
    }
    __syncthreads();

    if (spanic) {  // ultra-rare: re-stream all edges for this bucket (idempotent max)
        const int rb = r_index[b];
        const int* __restrict__ src = edge_index;
        const int* __restrict__ dst = edge_index + E;
        for (int e = t; e < E; e += TH2) {
            if (etype[e] == rb) {
                unsigned int d = (unsigned int)dst[e];
                if ((int)(d >> CSHIFT) == c)
                    atomicMax(&slice[d & cmask], __float_as_int(hb[src[e]]));
            }
        }
        __syncthreads();
    }

    // Plain coalesced store (out never read; covers clamp floor + empty segments).
    const int d0 = c << CSHIFT;
    int cnt = N - d0; if (cnt > csz) cnt = csz;
    int* __restrict__ ob = out + (size_t)b * N + d0;
    for (int i = t; i < cnt; i += TH2) ob[i] = slice[i];
}

// ===== Fallback for unsupported shapes / tiny ws =====

__global__ __launch_bounds__(256)
void zero_out_kernel(int* __restrict__ out, int n) {
    int i = (blockIdx.x * 256 + threadIdx.x) * 4;
    if (i + 3 < n) {
        v4i z = {0, 0, 0, 0};
        *reinterpret_cast<v4i*>(out + i) = z;
    } else {
        for (int j = i; j < n && j >= 0; ++j) out[j] = 0;
    }
}

__global__ __launch_bounds__(256)
void traverse_direct(const float* __restrict__ h,
                     const int* __restrict__ edge_index,
                     const int* __restrict__ etype,
                     const int* __restrict__ r_index,
                     int* __restrict__ out, int B, int N, int E) {
    __shared__ unsigned int smask[64];
    if (threadIdx.x < 64) {
        unsigned int m = 0;
        for (int b = 0; b < B; ++b)
            if (r_index[b] == (int)threadIdx.x) m |= (1u << b);
        smask[threadIdx.x] = m;
    }
    __syncthreads();
    const int* __restrict__ src = edge_index;
    const int* __restrict__ dst = edge_index + E;
    int e = blockIdx.x * blockDim.x + threadIdx.x;
    if (e < E) {
        unsigned int ty = (unsigned int)etype[e];
        unsigned int m = (ty < 64u) ? smask[ty] : 0u;
        while (m) {
            int b = __builtin_ctz(m); m &= m - 1;
            float v = h[(size_t)b * N + src[e]];
            atomicMax(out + (size_t)b * N + dst[e], __float_as_int(v));
        }
    }
}

extern "C" void kernel_launch(void* const* d_in, const int* in_sizes, int n_in,
                              void* d_out, int out_size, void* d_ws, size_t ws_size,
                              hipStream_t stream) {
    const float* h          = (const float*)d_in[0];
    const int*   edge_index = (const int*)d_in[1];
    const int*   etype      = (const int*)d_in[2];
    const int*   r_index    = (const int*)d_in[3];

    const int B = in_sizes[3];
    const int N = in_sizes[0] / B;
    const int E = in_sizes[2];
    const int nchunk = (N + (1 << CSHIFT) - 1) >> CSHIFT;
    const int nbkt = B * nchunk;
    int* out_i = (int*)d_out;

    // ws layout: ovcnt u32[NB1] (4KB pad) | store [nbkt][NB1][16] u32 | ovrec [NB1][OVCAP] uint2
    unsigned int* ovcnt = (unsigned int*)d_ws;
    unsigned int* store = ovcnt + 1024;
    const size_t store_words = (size_t)(nbkt > 0 ? nbkt : 1) * NB1 * 16;
    uint2* ovrec = (uint2*)(store + store_words);
    const size_t need_ws = 4096 + store_words * 4 + (size_t)NB1 * OVCAP * 8;

    const bool fast = (N <= (1 << 17)) && (B <= 32) && (B % 8 == 0) && (nbkt >= 1) &&
                      (nbkt <= MAXNBKT) && (ws_size >= need_ws) && (E >= 4) &&
                      (out_size == B * N);
    if (fast) {
        phase1_kernel<<<NB1, TH1, 0, stream>>>(
            edge_index, etype, r_index, ovcnt, ovrec, store,
            B, N, E, nchunk, nbkt);
        phase2_kernel<<<nbkt, TH2, 0, stream>>>(
            h, store, ovcnt, ovrec, edge_index, etype, r_index,
            B, N, E, nchunk, out_i);
    } else {
        const int nz = (out_size + 1023) / 1024;
        zero_out_kernel<<<nz, 256, 0, stream>>>(out_i, out_size);
        traverse_direct<<<(E + 255) / 256, 256, 0, stream>>>(
            h, edge_index, etype, r_index, out_i, B, N, E);
    }
}